// Round 5
// baseline (157.945 us; speedup 1.0000x reference)
//
#include <hip/hip_runtime.h>
#include <hip/hip_cooperative_groups.h>
#include <math.h>

namespace cg = cooperative_groups;

#define TWO_PI 6.28318530717958647692f
#define NT     512           // 8 waves per block
#define RPW    8             // conv: transforms per wave (64 / 8 waves)
#define PITCH  65            // LDS pitch for 64-wide transpose (conflict-free)
#define THRESH 10.0f
// unit-root recurrence constants
#define C64    0.995184726672196886f
#define S64    0.098017140329560602f
#define C4096  0.999998823451701879f
#define S4096  0.001533980186284766f

typedef float v2f __attribute__((ext_vector_type(2)));

__device__ __forceinline__ int brev6(int x) {
    return (int)(__brev((unsigned)x) >> 26);
}

// acc + a*b (complex), vector form -> v_pk_fma_f32 candidates
__device__ __forceinline__ v2f cmul_add(v2f a, v2f b, v2f acc) {
    acc += (v2f){a.x, a.x} * b;
    acc += (v2f){a.y, a.y} * (v2f){-b.y, b.x};
    return acc;
}

// Cross-lane 64-pt DIF FFT (radix-2). Natural-order input across lanes;
// output: lane l holds coefficient brev6(l). sign=-1 fwd, +1 inverse(unnorm).
template<int R>
__device__ __forceinline__ void fft64_dif(float (&re)[R], float (&im)[R],
                                          int lane, float sign) {
    #pragma unroll
    for (int h = 32; h >= 1; h >>= 1) {
        int j = lane & (h - 1);
        float ang = sign * (TWO_PI / 64.0f) * (float)(j * (32 / h));
        float wr, wi;
        __sincosf(ang, &wi, &wr);
        bool upper = (lane & h) != 0;
        float cwr = upper ? wr : 1.0f;
        float cwi = upper ? wi : 0.0f;
        float sgn = upper ? -1.0f : 1.0f;
        #pragma unroll
        for (int m = 0; m < R; ++m) {
            float orr = __shfl_xor(re[m], h, 64);
            float oii = __shfl_xor(im[m], h, 64);
            float ar = fmaf(sgn, re[m], orr);   // lower: a+b ; upper: a-b
            float ai = fmaf(sgn, im[m], oii);
            re[m] = ar * cwr - ai * cwi;        // upper gets *w, lower *1
            im[m] = ar * cwi + ai * cwr;
        }
    }
}

// Cross-lane 64-pt DIT FFT. Input bit-reversed across lanes (lane l holds
// element brev6(l)); natural-order output.
template<int R>
__device__ __forceinline__ void fft64_dit(float (&re)[R], float (&im)[R],
                                          int lane, float sign) {
    #pragma unroll
    for (int h = 1; h <= 32; h <<= 1) {
        int j = lane & (h - 1);
        float ang = sign * (TWO_PI / 64.0f) * (float)(j * (32 / h));
        float wr, wi;
        __sincosf(ang, &wi, &wr);
        bool upper = (lane & h) != 0;
        float cwr = upper ? wr : 1.0f;
        float cwi = upper ? wi : 0.0f;
        float sgn = upper ? -1.0f : 1.0f;
        #pragma unroll
        for (int m = 0; m < R; ++m) {
            float tr = re[m] * cwr - im[m] * cwi;  // upper pre-multiplies by w
            float ti = re[m] * cwi + im[m] * cwr;
            float orr = __shfl_xor(tr, h, 64);
            float oii = __shfl_xor(ti, h, 64);
            re[m] = fmaf(sgn, tr, orr);            // lower: u+t ; upper: u-t
            im[m] = fmaf(sgn, ti, oii);
        }
    }
}

// Single cooperative kernel: phase A (column FFT halves) -> grid sync ->
// phase B (row FFT + threshold) -> grid sync -> phase C (conv + iFFT).
__global__ __launch_bounds__(NT, 2) void fused_kernel(const float* __restrict__ x,
                                                      const float* __restrict__ W,
                                                      const float* __restrict__ b,
                                                      float* __restrict__ out,
                                                      float2* __restrict__ Xa,
                                                      float2* __restrict__ X) {
    cg::grid_group grid = cg::this_grid();
    __shared__ float sre[64 * PITCH];
    __shared__ float sim[64 * PITCH];
    const int tid  = threadIdx.x;
    const int lane = tid & 63;
    const int w    = tid >> 6;

    // ---------------- Phase A: per (task, half): column FFTs ----------------
    {
        const int task = blockIdx.x >> 1;
        const int h    = blockIdx.x & 1;
        const float* xr = x + (size_t)task * 62 * 62;
        for (int idx = tid; idx < 64 * 32; idx += NT) {
            int r = idx >> 5, j = idx & 31;
            int n2 = 32 * h + j;
            float v = 0.0f;
            if (r >= 1 && r <= 62 && n2 >= 1 && n2 <= 62)
                v = xr[(r - 1) * 62 + (n2 - 1)];
            sre[r * 33 + j] = v;
        }
        __syncthreads();
        float re[4], im[4];
        #pragma unroll
        for (int m = 0; m < 4; ++m) {
            re[m] = sre[lane * 33 + (w * 4 + m)];
            im[m] = 0.0f;
        }
        fft64_dif<4>(re, im, lane, -1.0f);
        __syncthreads();                 // input reads done before overwrite
        const int k1 = brev6(lane);
        #pragma unroll
        for (int m = 0; m < 4; ++m) {
            int j  = w * 4 + m;
            int n2 = 32 * h + j;
            float cr, ci;                // e^{-2pi i k1 n2 / 4096}
            __sincosf(-(TWO_PI / 4096.0f) * (float)(k1 * n2), &ci, &cr);
            sre[k1 * 33 + j] = re[m] * cr - im[m] * ci;
            sim[k1 * 33 + j] = re[m] * ci + im[m] * cr;
        }
        __syncthreads();
        float2* Arow = Xa + (size_t)task * 4096;
        for (int idx = tid; idx < 64 * 32; idx += NT) {
            int k = idx >> 5, j = idx & 31;
            Arow[k * 64 + 32 * h + j] =
                make_float2(sre[k * 33 + j], sim[k * 33 + j]);
        }
    }
    grid.sync();

    // ---------------- Phase B: row FFTs + threshold ----------------
    {
        const int task = blockIdx.x >> 1;
        const int h    = blockIdx.x & 1;
        const float2* Arow = Xa + (size_t)task * 4096;
        float re[4], im[4];
        #pragma unroll
        for (int m = 0; m < 4; ++m) {
            float2 xv = Arow[(32 * h + w * 4 + m) * 64 + lane];
            re[m] = xv.x; im[m] = xv.y;
        }
        fft64_dif<4>(re, im, lane, -1.0f);
        float2* Xrow = X + (size_t)task * 4096;
        #pragma unroll
        for (int m = 0; m < 4; ++m) {
            float rr = re[m], ii = im[m];
            if (fabsf(rr) < THRESH) { rr = 0.0f; ii = 0.0f; }
            Xrow[(32 * h + w * 4 + m) * 64 + lane] = make_float2(rr, ii);
        }
    }
    grid.sync();

    // ---------------- Phase C: conv + inverse FFT + store ----------------
    {
        const int t    = blockIdx.x >> 5;
        const int o    = blockIdx.x & 31;

        const int k2 = brev6(lane);
        float elr, eli;          // e^{+2pi i k2/64}
        __sincosf((TWO_PI / 64.0f) * (float)k2, &eli, &elr);

        v2f uv[RPW], vv[RPW], v2v[RPW];
        {
            float cur, cui, cvr, cvi;
            __sincosf((TWO_PI / 8.0f) * (float)w, &cui, &cur);
            __sincosf((TWO_PI / 512.0f) * (float)w, &cvi, &cvr);
            #pragma unroll
            for (int m = 0; m < RPW; ++m) {
                uv[m] = (v2f){cur, cui};
                float vvr = cvr * elr - cvi * eli;
                float vvi = cvr * eli + cvi * elr;
                vv[m]  = (v2f){vvr, vvi};
                v2v[m] = (v2f){vvr * vvr - vvi * vvi, 2.0f * vvr * vvi};
                float nur = cur * C64 - cui * S64;
                cui = cur * S64 + cui * C64; cur = nur;
                float nvr = cvr * C4096 - cvi * S4096;
                cvi = cvr * S4096 + cvi * C4096; cvr = nvr;
            }
        }

        v2f S[RPW];
        #pragma unroll
        for (int m = 0; m < RPW; ++m) S[m] = (v2f){0.0f, 0.0f};

        const float2* Xt = X + (size_t)t * 16 * 4096 + (w * (RPW * 64) + lane);
        const float*  wo = W + o * 144;      // block-uniform -> scalar loads

        v2f xb[RPW];
        #pragma unroll
        for (int m = 0; m < RPW; ++m) {
            float2 q = Xt[m * 64];
            xb[m] = (v2f){q.x, q.y};
        }
        #pragma unroll 1
        for (int c = 0; c < 16; ++c) {
            v2f xn[RPW];
            if (c < 15) {
                const float2* xp = Xt + (c + 1) * 4096;
                #pragma unroll
                for (int m = 0; m < RPW; ++m) {
                    float2 q = xp[m * 64];
                    xn[m] = (v2f){q.x, q.y};
                }
            }
            const float wa0 = wo[c*9+0], wa1 = wo[c*9+1], wa2 = wo[c*9+2];
            const float wa3 = wo[c*9+3], wa4 = wo[c*9+4], wa5 = wo[c*9+5];
            const float wa6 = wo[c*9+6], wa7 = wo[c*9+7], wa8 = wo[c*9+8];
            #pragma unroll
            for (int m = 0; m < RPW; ++m) {
                v2f v = vv[m], v2 = v2v[m], u = uv[m];
                v2f h0 = (v2f){wa0, 0.0f}; h0 += v * wa1; h0 += v2 * wa2;
                v2f h1 = (v2f){wa3, 0.0f}; h1 += v * wa4; h1 += v2 * wa5;
                v2f h2 = (v2f){wa6, 0.0f}; h2 += v * wa7; h2 += v2 * wa8;
                v2f in = cmul_add(u, h2, h1);
                v2f P  = cmul_add(u, in, h0);
                S[m]   = cmul_add(xb[m], P, S[m]);
            }
            #pragma unroll
            for (int m = 0; m < RPW; ++m) xb[m] = xn[m];
        }

        float re[RPW], im[RPW];
        #pragma unroll
        for (int m = 0; m < RPW; ++m) { re[m] = S[m].x; im[m] = S[m].y; }
        fft64_dit<RPW>(re, im, lane, +1.0f);
        {
            float cr, ci, sr, si;
            __sincosf((TWO_PI / 512.0f) * (float)(lane * w), &ci, &cr);
            __sincosf((TWO_PI / 4096.0f) * (float)lane, &si, &sr);
            #pragma unroll
            for (int m = 0; m < RPW; ++m) {
                float rr = re[m] * cr - im[m] * ci;
                im[m]    = re[m] * ci + im[m] * cr;
                re[m]    = rr;
                float nr = cr * sr - ci * si;
                ci = cr * si + ci * sr; cr = nr;
            }
        }
        #pragma unroll
        for (int m = 0; m < RPW; ++m) {
            int k1 = w * RPW + m;
            sre[k1 * PITCH + lane] = re[m];
            sim[k1 * PITCH + lane] = im[m];
        }
        __syncthreads();
        #pragma unroll
        for (int m = 0; m < RPW; ++m) {
            int n2 = w * RPW + m;
            re[m] = sre[lane * PITCH + n2];
            im[m] = sim[lane * PITCH + n2];
        }
        fft64_dif<RPW>(re, im, lane, +1.0f);
        __syncthreads();
        const int n1 = brev6(lane);
        #pragma unroll
        for (int m = 0; m < RPW; ++m) {
            int n2 = w * RPW + m;
            sre[n1 * PITCH + n2] = re[m];
        }
        __syncthreads();
        const float bias = b[o];
        float* orow = out + (size_t)blockIdx.x * 62 * 62;
        for (int idx = tid; idx < 62 * 62; idx += NT) {
            int r = idx / 62, s = idx - r * 62;
            orow[idx] = sre[r * PITCH + s] * (1.0f / 4096.0f) + bias;
        }
    }
}

extern "C" void kernel_launch(void* const* d_in, const int* in_sizes, int n_in,
                              void* d_out, int out_size, void* d_ws, size_t ws_size,
                              hipStream_t stream) {
    const float* x = (const float*)d_in[0];   // (8,16,62,62) f32
    const float* W = (const float*)d_in[1];   // (32,16,3,3)  f32
    const float* b = (const float*)d_in[2];   // (32,)        f32
    float* out = (float*)d_out;               // (8,32,62,62) f32
    float2* Xa = (float2*)d_ws;               // 128*4096 complex = 4 MB
    float2* X  = Xa + 128 * 4096;             // 4 MB more

    void* args[] = { (void*)&x, (void*)&W, (void*)&b,
                     (void*)&out, (void*)&Xa, (void*)&X };
    hipLaunchCooperativeKernel((const void*)fused_kernel, dim3(256), dim3(NT),
                               args, 0, stream);
}

// Round 6
// 86.386 us; speedup vs baseline: 1.8284x; 1.8284x over previous
//
#include <hip/hip_runtime.h>
#include <math.h>

#define TWO_PI 6.28318530717958647692f
#define NT     1024          // 16 waves per block -> 4 waves/SIMD at 1 block/CU
#define RPW    4             // conv: k-rows per wave (64 rows / 16 waves)
#define PITCH  65            // LDS pitch for 64-wide transpose (conflict-free)
#define THRESH 10.0f
// unit-root recurrence constants (step = one k1 increment)
#define C64    0.995184726672196886f
#define S64    0.098017140329560602f
#define C4096  0.999998823451701879f
#define S4096  0.001533980186284766f

typedef float v2f __attribute__((ext_vector_type(2)));

__device__ __forceinline__ int brev6(int x) {
    return (int)(__brev((unsigned)x) >> 26);
}

// acc + a*b (complex), vector form
__device__ __forceinline__ v2f cmul_add(v2f a, v2f b, v2f acc) {
    acc += (v2f){a.x, a.x} * b;
    acc += (v2f){a.y, a.y} * (v2f){-b.y, b.x};
    return acc;
}

// Cross-lane 64-pt DIF FFT (radix-2). Natural-order input across lanes;
// output: lane l holds coefficient brev6(l). sign=-1 fwd, +1 inverse(unnorm).
template<int R>
__device__ __forceinline__ void fft64_dif(float (&re)[R], float (&im)[R],
                                          int lane, float sign) {
    #pragma unroll
    for (int h = 32; h >= 1; h >>= 1) {
        int j = lane & (h - 1);
        float ang = sign * (TWO_PI / 64.0f) * (float)(j * (32 / h));
        float wr, wi;
        __sincosf(ang, &wi, &wr);
        bool upper = (lane & h) != 0;
        float cwr = upper ? wr : 1.0f;
        float cwi = upper ? wi : 0.0f;
        float sgn = upper ? -1.0f : 1.0f;
        #pragma unroll
        for (int m = 0; m < R; ++m) {
            float orr = __shfl_xor(re[m], h, 64);
            float oii = __shfl_xor(im[m], h, 64);
            float ar = fmaf(sgn, re[m], orr);   // lower: a+b ; upper: a-b
            float ai = fmaf(sgn, im[m], oii);
            re[m] = ar * cwr - ai * cwi;        // upper gets *w, lower *1
            im[m] = ar * cwi + ai * cwr;
        }
    }
}

// Cross-lane 64-pt DIT FFT. Input bit-reversed across lanes (lane l holds
// element brev6(l)); natural-order output.
template<int R>
__device__ __forceinline__ void fft64_dit(float (&re)[R], float (&im)[R],
                                          int lane, float sign) {
    #pragma unroll
    for (int h = 1; h <= 32; h <<= 1) {
        int j = lane & (h - 1);
        float ang = sign * (TWO_PI / 64.0f) * (float)(j * (32 / h));
        float wr, wi;
        __sincosf(ang, &wi, &wr);
        bool upper = (lane & h) != 0;
        float cwr = upper ? wr : 1.0f;
        float cwi = upper ? wi : 0.0f;
        float sgn = upper ? -1.0f : 1.0f;
        #pragma unroll
        for (int m = 0; m < R; ++m) {
            float tr = re[m] * cwr - im[m] * cwi;  // upper pre-multiplies by w
            float ti = re[m] * cwi + im[m] * cwr;
            float orr = __shfl_xor(tr, h, 64);
            float oii = __shfl_xor(ti, h, 64);
            re[m] = fmaf(sgn, tr, orr);            // lower: u+t ; upper: u-t
            im[m] = fmaf(sgn, ti, oii);
        }
    }
}

// fwdA: 256 blocks, 2 per (t,c); block handles 32 columns n2. Column FFT over
// n1 + mid twiddle, LDS transpose, write Xa[task][k1][n2] (k1 natural).
__global__ __launch_bounds__(NT) void fwdA_kernel(const float* __restrict__ x,
                                                  float2* __restrict__ Xa) {
    __shared__ float sre[64 * 33];
    __shared__ float sim[64 * 33];
    const int task = blockIdx.x >> 1;
    const int h    = blockIdx.x & 1;
    const int tid  = threadIdx.x;
    const int lane = tid & 63;
    const int w    = tid >> 6;          // 0..15
    const float* xr = x + (size_t)task * 62 * 62;
    for (int idx = tid; idx < 64 * 32; idx += NT) {
        int r = idx >> 5, j = idx & 31;
        int n2 = 32 * h + j;
        float v = 0.0f;
        if (r >= 1 && r <= 62 && n2 >= 1 && n2 <= 62)
            v = xr[(r - 1) * 62 + (n2 - 1)];
        sre[r * 33 + j] = v;
    }
    __syncthreads();
    float re[2], im[2];
    #pragma unroll
    for (int m = 0; m < 2; ++m) {
        re[m] = sre[lane * 33 + (w * 2 + m)];
        im[m] = 0.0f;
    }
    fft64_dif<2>(re, im, lane, -1.0f);
    __syncthreads();                 // input reads done before overwrite
    const int k1 = brev6(lane);
    #pragma unroll
    for (int m = 0; m < 2; ++m) {
        int j  = w * 2 + m;
        int n2 = 32 * h + j;
        float cr, ci;                // e^{-2pi i k1 n2 / 4096}
        __sincosf(-(TWO_PI / 4096.0f) * (float)(k1 * n2), &ci, &cr);
        sre[k1 * 33 + j] = re[m] * cr - im[m] * ci;
        sim[k1 * 33 + j] = re[m] * ci + im[m] * cr;
    }
    __syncthreads();
    float2* Arow = Xa + (size_t)task * 4096;
    for (int idx = tid; idx < 64 * 32; idx += NT) {
        int k = idx >> 5, j = idx & 31;
        Arow[k * 64 + 32 * h + j] = make_float2(sre[k * 33 + j], sim[k * 33 + j]);
    }
}

// fwdB: 256 blocks, 2 per (t,c); block handles 32 k1-rows. Row FFT over n2,
// threshold, store X[task][k1][l] where value = spectrum[k1 + 64*brev6(l)].
__global__ __launch_bounds__(NT) void fwdB_kernel(const float2* __restrict__ Xa,
                                                  float2* __restrict__ X) {
    const int task = blockIdx.x >> 1;
    const int h    = blockIdx.x & 1;
    const int tid  = threadIdx.x;
    const int lane = tid & 63;
    const int w    = tid >> 6;          // 0..15
    const float2* Arow = Xa + (size_t)task * 4096;
    float re[2], im[2];
    #pragma unroll
    for (int m = 0; m < 2; ++m) {
        float2 xv = Arow[(32 * h + w * 2 + m) * 64 + lane];
        re[m] = xv.x; im[m] = xv.y;
    }
    fft64_dif<2>(re, im, lane, -1.0f);
    float2* Xrow = X + (size_t)task * 4096;
    #pragma unroll
    for (int m = 0; m < 2; ++m) {
        float rr = re[m], ii = im[m];
        if (fabsf(rr) < THRESH) { rr = 0.0f; ii = 0.0f; }
        Xrow[(32 * h + w * 2 + m) * 64 + lane] = make_float2(rr, ii);
    }
}

// conv: per (t,o): S[k] = sum_c X[t,c,k]*conj(Wf[o,c,k]) via per-c double
// Horner, inverse four-step FFT, crop + bias. 16 waves, 4 k-rows per wave.
__global__ __launch_bounds__(NT, 4) void conv_kernel(const float2* __restrict__ X,
                                                     const float* __restrict__ W,
                                                     const float* __restrict__ b,
                                                     float* __restrict__ out) {
    __shared__ float sre[64 * PITCH];
    __shared__ float sim[64 * PITCH];
    const int t    = blockIdx.x >> 5;
    const int o    = blockIdx.x & 31;
    const int tid  = threadIdx.x;
    const int lane = tid & 63;
    const int w    = tid >> 6;          // 0..15

    const int k2 = brev6(lane);
    float elr, eli;          // e^{+2pi i k2/64}
    __sincosf((TWO_PI / 64.0f) * (float)k2, &eli, &elr);

    // Per-m twiddles (k1 = w*4+m): u = e^{2pi i k1/64}, v = e^{2pi i k/4096},
    // v2 = v^2, by recurrence (2 sincos total).
    v2f uv[RPW], vv[RPW], v2v[RPW];
    {
        float cur, cui, cvr, cvi;
        __sincosf((TWO_PI / 16.0f) * (float)w, &cui, &cur);    // u at m=0: 4w/64
        __sincosf((TWO_PI / 1024.0f) * (float)w, &cvi, &cvr);  // vk at m=0: 4w/4096
        #pragma unroll
        for (int m = 0; m < RPW; ++m) {
            uv[m] = (v2f){cur, cui};
            float vvr = cvr * elr - cvi * eli;                 // v = vk*el
            float vvi = cvr * eli + cvi * elr;
            vv[m]  = (v2f){vvr, vvi};
            v2v[m] = (v2f){vvr * vvr - vvi * vvi, 2.0f * vvr * vvi};
            float nur = cur * C64 - cui * S64;
            cui = cur * S64 + cui * C64; cur = nur;
            float nvr = cvr * C4096 - cvi * S4096;
            cvi = cvr * S4096 + cvi * C4096; cvr = nvr;
        }
    }

    v2f S[RPW];
    #pragma unroll
    for (int m = 0; m < RPW; ++m) S[m] = (v2f){0.0f, 0.0f};

    const float2* Xt = X + (size_t)t * 16 * 4096 + (w * (RPW * 64) + lane);
    const float*  wo = W + o * 144;          // block-uniform -> scalar loads

    v2f xb[RPW];
    #pragma unroll
    for (int m = 0; m < RPW; ++m) {
        float2 q = Xt[m * 64];
        xb[m] = (v2f){q.x, q.y};
    }
    #pragma unroll 1
    for (int c = 0; c < 16; ++c) {
        v2f xn[RPW];
        if (c < 15) {
            const float2* xp = Xt + (c + 1) * 4096;
            #pragma unroll
            for (int m = 0; m < RPW; ++m) {
                float2 q = xp[m * 64];
                xn[m] = (v2f){q.x, q.y};
            }
        }
        const float wa0 = wo[c*9+0], wa1 = wo[c*9+1], wa2 = wo[c*9+2];
        const float wa3 = wo[c*9+3], wa4 = wo[c*9+4], wa5 = wo[c*9+5];
        const float wa6 = wo[c*9+6], wa7 = wo[c*9+7], wa8 = wo[c*9+8];
        #pragma unroll
        for (int m = 0; m < RPW; ++m) {
            v2f v = vv[m], v2 = v2v[m], u = uv[m];
            // h_i = W[i][0] + v*W[i][1] + v2*W[i][2]  (real coefficients)
            v2f h0 = (v2f){wa0, 0.0f}; h0 += v * wa1; h0 += v2 * wa2;
            v2f h1 = (v2f){wa3, 0.0f}; h1 += v * wa4; h1 += v2 * wa5;
            v2f h2 = (v2f){wa6, 0.0f}; h2 += v * wa7; h2 += v2 * wa8;
            // P = h0 + u*(h1 + u*h2); S += X * P
            v2f in = cmul_add(u, h2, h1);
            v2f P  = cmul_add(u, in, h0);
            S[m]   = cmul_add(xb[m], P, S[m]);
        }
        #pragma unroll
        for (int m = 0; m < RPW; ++m) xb[m] = xn[m];
    }

    float re[RPW], im[RPW];
    #pragma unroll
    for (int m = 0; m < RPW; ++m) { re[m] = S[m].x; im[m] = S[m].y; }
    // Phase 1: inverse FFT over k2 (lanes hold k2 = brev6(l) -> DIT).
    fft64_dit<RPW>(re, im, lane, +1.0f);
    // Mid twiddle: * e^{+2pi i n2 k1 / 4096}, n2 = lane, recurrence over m.
    {
        float cr, ci, sr, si;
        __sincosf((TWO_PI / 1024.0f) * (float)(lane * w), &ci, &cr);  // lane*4w/4096
        __sincosf((TWO_PI / 4096.0f) * (float)lane, &si, &sr);
        #pragma unroll
        for (int m = 0; m < RPW; ++m) {
            float rr = re[m] * cr - im[m] * ci;
            im[m]    = re[m] * ci + im[m] * cr;
            re[m]    = rr;
            float nr = cr * sr - ci * si;
            ci = cr * si + ci * sr; cr = nr;
        }
    }
    // Transpose through LDS: write [k1][n2].
    #pragma unroll
    for (int m = 0; m < RPW; ++m) {
        int k1 = w * RPW + m;
        sre[k1 * PITCH + lane] = re[m];
        sim[k1 * PITCH + lane] = im[m];
    }
    __syncthreads();
    // Phase 2: inverse FFT over k1 (lane = k1), columns n2 = w*RPW + m.
    #pragma unroll
    for (int m = 0; m < RPW; ++m) {
        int n2 = w * RPW + m;
        re[m] = sre[lane * PITCH + n2];
        im[m] = sim[lane * PITCH + n2];
    }
    fft64_dif<RPW>(re, im, lane, +1.0f);
    __syncthreads();   // phase-2 reads done before y overwrite
    // Lane l holds y[n1 = brev6(l)][n2]; unscramble via LDS for coalesced store.
    const int n1 = brev6(lane);
    #pragma unroll
    for (int m = 0; m < RPW; ++m) {
        int n2 = w * RPW + m;
        sre[n1 * PITCH + n2] = re[m];
    }
    __syncthreads();
    const float bias = b[o];
    float* orow = out + (size_t)blockIdx.x * 62 * 62;
    for (int idx = tid; idx < 62 * 62; idx += NT) {
        int r = idx / 62, s = idx - r * 62;
        orow[idx] = sre[r * PITCH + s] * (1.0f / 4096.0f) + bias;
    }
}

extern "C" void kernel_launch(void* const* d_in, const int* in_sizes, int n_in,
                              void* d_out, int out_size, void* d_ws, size_t ws_size,
                              hipStream_t stream) {
    const float* x = (const float*)d_in[0];   // (8,16,62,62) f32
    const float* W = (const float*)d_in[1];   // (32,16,3,3)  f32
    const float* b = (const float*)d_in[2];   // (32,)        f32
    float* out = (float*)d_out;               // (8,32,62,62) f32
    float2* Xa = (float2*)d_ws;               // 128*4096 complex = 4 MB
    float2* X  = Xa + 128 * 4096;             // 4 MB more

    fwdA_kernel<<<dim3(256), dim3(NT), 0, stream>>>(x, Xa);
    fwdB_kernel<<<dim3(256), dim3(NT), 0, stream>>>(Xa, X);
    conv_kernel<<<dim3(256), dim3(NT), 0, stream>>>(X, W, b, out);
}